// Round 1
// baseline (44.764 us; speedup 1.0000x reference)
//
#include <hip/hip_runtime.h>

#define D_DIM 4096
#define H_DIM 4096
#define HB 16          // rows (h) per block
#define IB 256         // columns (i) per tile
#define SP 260         // padded LDS stride: mult of 4 (b128-aligned), 260%32=4 -> <=2-way conflicts (free)
#define NBLK (H_DIM / HB)   // 256 blocks
#define NT (D_DIM / IB)     // 16 tiles

__device__ __forceinline__ float fast_sigmoid(float a) {
    return __builtin_amdgcn_rcpf(1.0f + __expf(-a));
}

// Grid: NBLK x 1024 threads (16 waves). Wave wv owns row h0+wv's prefix scan.
template <bool ATOMIC>
__global__ __launch_bounds__(1024, 1) void nade_main_kernel(
    const float* __restrict__ x,
    const float* __restrict__ w,
    const float* __restrict__ v,
    const float* __restrict__ c,
    float* __restrict__ part)
{
    __shared__ float S[2][HB][SP];     // double-buffered sigmoid tiles
    __shared__ float partial[D_DIM];   // block-partial logits
    __shared__ float xs[D_DIM];

    const int tid  = threadIdx.x;
    const int wv   = tid >> 6;     // wave id = local row 0..15
    const int lane = tid & 63;
    const int q    = tid & 3;      // h-quad for reduce phase
    const int il   = tid >> 2;     // column-in-tile for reduce phase 0..255
    const int h0   = blockIdx.x * HB;

    for (int i = tid; i < D_DIM; i += 1024) {
        xs[i] = x[i];
        partial[i] = 0.0f;
    }
    const int h = h0 + wv;
    const float* wrow = w + (size_t)h * D_DIM;
    float carry = c[h];
    __syncthreads();

    auto scan_tile = [&](int t, int buf) {
        const int i0 = t * IB;
        float4 wp = *reinterpret_cast<const float4*>(wrow + i0 + 4 * lane);
        float4 xp = *reinterpret_cast<const float4*>(&xs[i0 + 4 * lane]);
        float p0 = wp.x * xp.x, p1 = wp.y * xp.y, p2 = wp.z * xp.z, p3 = wp.w * xp.w;
        float sum4 = p0 + p1 + p2 + p3;
        float incl = sum4;
        #pragma unroll
        for (int off = 1; off < 64; off <<= 1) {
            float tv = __shfl_up(incl, off, 64);
            incl += (lane >= off) ? tv : 0.0f;
        }
        float e = carry + incl - sum4;   // exclusive prefix + carry
        float a0 = e;
        float a1 = a0 + p0;
        float a2 = a1 + p1;
        float a3 = a2 + p2;
        float4 sv;
        sv.x = fast_sigmoid(a0);
        sv.y = fast_sigmoid(a1);
        sv.z = fast_sigmoid(a2);
        sv.w = fast_sigmoid(a3);
        *reinterpret_cast<float4*>(&S[buf][wv][4 * lane]) = sv;
        carry += __shfl(incl, 63, 64);   // tile total
    };

    scan_tile(0, 0);

    for (int t = 0; t < NT; ++t) {
        __syncthreads();
        if (t + 1 < NT) scan_tile(t + 1, (t + 1) & 1);
        // reduce tile t: partial[i] += sum_h v[i,h] * S[h][i]
        const int i = t * IB + il;
        float4 vp = *reinterpret_cast<const float4*>(v + (size_t)i * H_DIM + h0 + 4 * q);
        const float* Sb = &S[t & 1][0][0];
        float s0 = Sb[(4 * q + 0) * SP + il];
        float s1 = Sb[(4 * q + 1) * SP + il];
        float s2 = Sb[(4 * q + 2) * SP + il];
        float s3 = Sb[(4 * q + 3) * SP + il];
        float acc = vp.x * s0 + vp.y * s1 + vp.z * s2 + vp.w * s3;
        acc += __shfl_xor(acc, 1, 64);
        acc += __shfl_xor(acc, 2, 64);
        if (q == 0) partial[i] += acc;
    }
    __syncthreads();

    if (ATOMIC) {
        for (int i = tid; i < D_DIM; i += 1024)
            atomicAdd(&part[i], partial[i]);
    } else {
        for (int i = tid; i < D_DIM; i += 1024)
            part[(size_t)blockIdx.x * D_DIM + i] = partial[i];
    }
}

// Grid: D/64 blocks x 1024 threads. Sums the [NBLK][D] partial matrix (coalesced).
__global__ __launch_bounds__(1024, 1) void nade_reduce_kernel(
    const float* __restrict__ part,
    const float* __restrict__ b,
    float* __restrict__ out)
{
    __shared__ float red[16][64];
    const int tid = threadIdx.x;
    const int bg  = tid >> 6;      // wave id 0..15
    const int il  = tid & 63;
    const int i   = blockIdx.x * 64 + il;
    float s = 0.0f;
    #pragma unroll
    for (int j = 0; j < NBLK / 16; ++j)
        s += part[(size_t)(bg * (NBLK / 16) + j) * D_DIM + i];
    red[bg][il] = s;
    __syncthreads();
    if (tid < 64) {
        float t = b[blockIdx.x * 64 + tid];
        #pragma unroll
        for (int j = 0; j < 16; ++j) t += red[j][tid];
        out[blockIdx.x * 64 + tid] = fast_sigmoid(t);
    }
}

__global__ __launch_bounds__(256, 1) void nade_final_atomic(
    const float* __restrict__ logits,
    const float* __restrict__ b,
    float* __restrict__ out)
{
    const int i = blockIdx.x * 256 + threadIdx.x;
    out[i] = fast_sigmoid(logits[i] + b[i]);
}

extern "C" void kernel_launch(void* const* d_in, const int* in_sizes, int n_in,
                              void* d_out, int out_size, void* d_ws, size_t ws_size,
                              hipStream_t stream)
{
    const float* x = (const float*)d_in[0];
    const float* w = (const float*)d_in[1];
    const float* b = (const float*)d_in[2];
    const float* v = (const float*)d_in[3];
    const float* c = (const float*)d_in[4];
    float* out = (float*)d_out;
    float* ws  = (float*)d_ws;

    const size_t need = (size_t)NBLK * D_DIM * sizeof(float);
    if (ws_size >= need) {
        nade_main_kernel<false><<<NBLK, 1024, 0, stream>>>(x, w, v, c, ws);
        nade_reduce_kernel<<<D_DIM / 64, 1024, 0, stream>>>(ws, b, out);
    } else {
        hipMemsetAsync(d_ws, 0, D_DIM * sizeof(float), stream);
        nade_main_kernel<true><<<NBLK, 1024, 0, stream>>>(x, w, v, c, ws);
        nade_final_atomic<<<D_DIM / 256, 256, 0, stream>>>(ws, b, out);
    }
}